// Round 1
// baseline (767.033 us; speedup 1.0000x reference)
//
#include <hip/hip_runtime.h>
#include <hip/hip_bf16.h>

#define DEV __device__ __forceinline__

constexpr int NC = 200000;   // clauses
constexpr int NF = 64;       // features
constexpr int NH = 128;      // hidden
constexpr int NS = 512;      // SEL steps

// ---- workspace layout (float units) ----
constexpr int OF_CFG   = 0;                 // int[16]: [0]=float_kind(0=f32,1=bf16), [1]=mask_width(1/2/4 bytes)
constexpr int OF_W1    = 16;                // 8192 fp32 (converted)
constexpr int OF_B1    = OF_W1 + NF * NH;   // 128
constexpr int OF_W2K   = OF_B1 + NH;        // 128  (W2 @ key_w)
constexpr int OF_B2K   = OF_W2K + NH;       // 1    (b2 . key_w)
constexpr int OF_MAX   = OF_B2K + 1;        // 1    (flipped-uint global max of logits)
constexpr int OF_ACCE  = OF_MAX + 1;        // 512  sum exp(l-M) over passive
constexpr int OF_ACCP  = OF_ACCE + NS;      // 512  sum logits over passive&proof
constexpr int OF_ACCC  = OF_ACCP + NS;      // 512  count passive&proof
constexpr int OF_LOGIT = 16384;             // 200000
constexpr int OF_E     = OF_LOGIT + NC;     // 200000 exp(l-M)
constexpr int OF_PL    = OF_E + NC;         // 200000 proof? l : 0
constexpr int OF_PC    = OF_PL + NC;        // 200000 proof? 1 : 0
// total = OF_PC + NC = 816384 floats = ~3.2 MB of d_ws

DEV float bf2f(unsigned short u) { return __uint_as_float(((unsigned)u) << 16); }

DEV float loadF(const void* p, int i, int fk) {
    return fk ? bf2f(((const unsigned short*)p)[i]) : ((const float*)p)[i];
}

// order-preserving float->uint map for atomicMax
DEV unsigned flipf(float x) {
    unsigned u = __float_as_uint(x);
    return (u & 0x80000000u) ? ~u : (u | 0x80000000u);
}
DEV float unflipf(unsigned u) {
    unsigned b = (u & 0x80000000u) ? (u ^ 0x80000000u) : ~u;
    return __uint_as_float(b);
}

DEV bool okhalf(unsigned h) { return h == 0u || h == 1u || h == 0x3F80u || h == 0x3C00u; }

// ---------------- K0: dtype probe + small precompute + zero accumulators ----------------
__global__ void k_probe(const void* features, const void* W1, const void* b1,
                        const void* W2, const void* b2, const void* keyw,
                        const void* sel, float* ws) {
    __shared__ int scfg[2];
    __shared__ float kw[NH];
    int tx = threadIdx.x;
    if (tx == 0) {
        // float kind: count tiny bf16-exponent patterns among first 256 u16 of features.
        // true-bf16 N(0,1) data: ~0 tiny; fp32 data read as u16: ~40% of low halves tiny.
        const unsigned short* u = (const unsigned short*)features;
        int tiny = 0;
        for (int i = 0; i < 256; i++) {
            unsigned e = (u[i] >> 7) & 0xFFu;  // exponent field as bf16
            if (e < 100u) tiny++;
        }
        scfg[0] = (tiny >= 8) ? 0 : 1;  // 0=fp32, 1=bf16
        // mask element width: word/half patterns over first 256 words of sel_mask
        const unsigned* w = (const unsigned*)sel;
        bool w4 = true, w2 = true;
        for (int i = 0; i < 256; i++) {
            unsigned v = w[i];
            if (!(v == 0u || v == 1u || v == 0x3F800000u)) w4 = false;
            if (!(okhalf(v & 0xFFFFu) && okhalf(v >> 16))) w2 = false;
        }
        scfg[1] = w4 ? 4 : (w2 ? 2 : 1);
    }
    __syncthreads();
    int fk = scfg[0];
    if (tx < 2) ((int*)ws)[tx] = scfg[tx];
    if (tx < NH) kw[tx] = loadF(keyw, tx, fk);
    for (int i = tx; i < NF * NH; i += blockDim.x) ws[OF_W1 + i] = loadF(W1, i, fk);
    if (tx < NH) ws[OF_B1 + tx] = loadF(b1, tx, fk);
    __syncthreads();
    if (tx < NH) {
        float s = 0.f;
        for (int k = 0; k < NH; k++) s += loadF(W2, tx * NH + k, fk) * kw[k];
        ws[OF_W2K + tx] = s;
    }
    if (tx == 0) {
        float s = 0.f;
        for (int k = 0; k < NH; k++) s += loadF(b2, k, fk) * kw[k];
        ws[OF_B2K] = s;
        ((unsigned*)ws)[OF_MAX] = 0u;  // flipped -inf sentinel (< flip of any real logit)
    }
    for (int i = tx; i < 3 * NS; i += blockDim.x) ws[OF_ACCE + i] = 0.f;
}

// ---------------- K1: logits[n] = relu(F@W1+b1).w2k + b2k, + global max ----------------
__global__ __launch_bounds__(256) void k_logits(const void* features, float* ws) {
    __shared__ float sW1[NF * NH];
    __shared__ float sB1[NH];
    __shared__ float sWK[NH];
    __shared__ float sred[4];
    int tx = threadIdx.x;
    int fk = ((const int*)ws)[0];
    for (int i = tx; i < NF * NH; i += 256) sW1[i] = ws[OF_W1 + i];
    if (tx < NH) { sB1[tx] = ws[OF_B1 + tx]; sWK[tx] = ws[OF_W2K + tx]; }
    float b2k = ws[OF_B2K];
    __syncthreads();
    int n = blockIdx.x * 256 + tx;
    float acc = -3.0e38f;
    if (n < NC) {
        float feat[NF];
        if (fk) {
            const uint4* fp = (const uint4*)((const unsigned short*)features + (size_t)n * NF);
            #pragma unroll
            for (int q = 0; q < 8; q++) {
                uint4 v = fp[q];
                unsigned vv[4] = {v.x, v.y, v.z, v.w};
                #pragma unroll
                for (int h = 0; h < 4; h++) {
                    feat[q * 8 + h * 2 + 0] = __uint_as_float(vv[h] << 16);
                    feat[q * 8 + h * 2 + 1] = __uint_as_float(vv[h] & 0xFFFF0000u);
                }
            }
        } else {
            const float4* fp = (const float4*)((const float*)features + (size_t)n * NF);
            #pragma unroll
            for (int q = 0; q < 16; q++) {
                float4 v = fp[q];
                feat[q * 4 + 0] = v.x; feat[q * 4 + 1] = v.y;
                feat[q * 4 + 2] = v.z; feat[q * 4 + 3] = v.w;
            }
        }
        acc = b2k;
        #pragma unroll 2
        for (int jc = 0; jc < NH / 4; jc++) {
            float d0 = sB1[jc * 4 + 0], d1 = sB1[jc * 4 + 1];
            float d2 = sB1[jc * 4 + 2], d3 = sB1[jc * 4 + 3];
            #pragma unroll
            for (int f = 0; f < NF; f++) {
                float4 w = *(const float4*)&sW1[f * NH + jc * 4];  // wave-uniform -> broadcast
                d0 += feat[f] * w.x; d1 += feat[f] * w.y;
                d2 += feat[f] * w.z; d3 += feat[f] * w.w;
            }
            acc += fmaxf(d0, 0.f) * sWK[jc * 4 + 0] + fmaxf(d1, 0.f) * sWK[jc * 4 + 1]
                 + fmaxf(d2, 0.f) * sWK[jc * 4 + 2] + fmaxf(d3, 0.f) * sWK[jc * 4 + 3];
        }
        ws[OF_LOGIT + n] = acc;
    }
    // block max -> global atomicMax (flipped uint)
    float m = acc;
    #pragma unroll
    for (int k = 1; k < 64; k <<= 1) m = fmaxf(m, __shfl_xor(m, k, 64));
    if ((tx & 63) == 0) sred[tx >> 6] = m;
    __syncthreads();
    if (tx == 0) {
        m = fmaxf(fmaxf(sred[0], sred[1]), fmaxf(sred[2], sred[3]));
        atomicMax((unsigned*)ws + OF_MAX, flipf(m));
    }
}

// ---------------- K2: e = exp(l - M), proof-gated logits / counts ----------------
__global__ void k_prep(const void* proof, float* ws) {
    int n = blockIdx.x * 256 + threadIdx.x;
    if (n >= NC) return;
    int mw = ((const int*)ws)[1];
    float M = unflipf(((const unsigned*)ws)[OF_MAX]);
    float l = ws[OF_LOGIT + n];
    ws[OF_E + n] = __expf(l - M);
    bool pf;
    if (mw == 1)      pf = ((const unsigned char*)proof)[n] != 0;
    else if (mw == 2) pf = ((const unsigned short*)proof)[n] != 0;
    else              pf = ((const unsigned*)proof)[n] != 0;
    ws[OF_PL + n] = pf ? l : 0.f;
    ws[OF_PC + n] = pf ? 1.f : 0.f;
}

// ---------------- K3: the big masked accumulation over sel_mask ----------------
constexpr int NT_N = 16;            // n per thread (register-resident e/pl/pc)
constexpr int BL_N = 256 * NT_N;    // 4096 n per block
constexpr int SG = 32;              // s per block

template<int MW>
DEV void bloop(const void* sel, int s0, int baddr,
               const float (&e)[NT_N], const float (&pl)[NT_N], const float (&pc)[NT_N],
               float* ws) {
    for (int si = 0; si < SG; si++) {
        int s = s0 + si;
        size_t off = (size_t)s * NC + (size_t)baddr;
        float m[NT_N];
        if (MW == 1) {
            uint4 w = *(const uint4*)((const unsigned char*)sel + off);
            unsigned v[4] = {w.x, w.y, w.z, w.w};
            #pragma unroll
            for (int q = 0; q < 4; q++)
                #pragma unroll
                for (int b = 0; b < 4; b++)
                    m[q * 4 + b] = ((v[q] >> (8 * b)) & 0xFFu) ? 1.f : 0.f;
        } else if (MW == 2) {
            const uint4* p = (const uint4*)((const unsigned short*)sel + off);
            #pragma unroll
            for (int h = 0; h < 2; h++) {
                uint4 w = p[h];
                unsigned v[4] = {w.x, w.y, w.z, w.w};
                #pragma unroll
                for (int q = 0; q < 4; q++) {
                    m[h * 8 + q * 2 + 0] = (v[q] & 0xFFFFu) ? 1.f : 0.f;
                    m[h * 8 + q * 2 + 1] = (v[q] >> 16) ? 1.f : 0.f;
                }
            }
        } else {
            const uint4* p = (const uint4*)((const unsigned*)sel + off);
            #pragma unroll
            for (int q = 0; q < 4; q++) {
                uint4 w = p[q];
                m[q * 4 + 0] = w.x ? 1.f : 0.f; m[q * 4 + 1] = w.y ? 1.f : 0.f;
                m[q * 4 + 2] = w.z ? 1.f : 0.f; m[q * 4 + 3] = w.w ? 1.f : 0.f;
            }
        }
        float se = 0.f, sp = 0.f, sc = 0.f;
        #pragma unroll
        for (int i = 0; i < NT_N; i++) {
            se += m[i] * e[i]; sp += m[i] * pl[i]; sc += m[i] * pc[i];
        }
        #pragma unroll
        for (int k = 1; k < 64; k <<= 1) {
            se += __shfl_xor(se, k, 64);
            sp += __shfl_xor(sp, k, 64);
            sc += __shfl_xor(sc, k, 64);
        }
        if ((threadIdx.x & 63) == 0) {
            atomicAdd(&ws[OF_ACCE + s], se);
            atomicAdd(&ws[OF_ACCP + s], sp);
            atomicAdd(&ws[OF_ACCC + s], sc);
        }
    }
}

__global__ __launch_bounds__(256) void k_phaseB(const void* sel, float* ws) {
    int tx = threadIdx.x;
    int base = blockIdx.x * BL_N + tx * NT_N;
    int s0 = blockIdx.y * SG;
    bool active = base < NC;                 // NC % 16 == 0, so active threads are fully valid
    int baddr = active ? base : 0;
    float e[NT_N], pl[NT_N], pc[NT_N];
    #pragma unroll
    for (int q = 0; q < 4; q++) {
        float4 ve = active ? ((const float4*)&ws[OF_E + baddr])[q]  : make_float4(0, 0, 0, 0);
        float4 vp = active ? ((const float4*)&ws[OF_PL + baddr])[q] : make_float4(0, 0, 0, 0);
        float4 vc = active ? ((const float4*)&ws[OF_PC + baddr])[q] : make_float4(0, 0, 0, 0);
        e[q * 4 + 0] = ve.x; e[q * 4 + 1] = ve.y; e[q * 4 + 2] = ve.z; e[q * 4 + 3] = ve.w;
        pl[q * 4 + 0] = vp.x; pl[q * 4 + 1] = vp.y; pl[q * 4 + 2] = vp.z; pl[q * 4 + 3] = vp.w;
        pc[q * 4 + 0] = vc.x; pc[q * 4 + 1] = vc.y; pc[q * 4 + 2] = vc.z; pc[q * 4 + 3] = vc.w;
    }
    int mw = ((const int*)ws)[1];
    if (mw == 1)      bloop<1>(sel, s0, baddr, e, pl, pc, ws);
    else if (mw == 2) bloop<2>(sel, s0, baddr, e, pl, pc, ws);
    else              bloop<4>(sel, s0, baddr, e, pl, pc, ws);
}

// ---------------- K4: per-step loss + mean, cast to output dtype ----------------
__global__ void k_final(float* ws, void* out) {
    __shared__ float sred[256];
    int tx = threadIdx.x;
    float M = unflipf(((const unsigned*)ws)[OF_MAX]);
    float sum = 0.f;
    for (int s = tx; s < NS; s += 256) {
        float lse = M + logf(ws[OF_ACCE + s]);
        sum += lse - ws[OF_ACCP + s] / ws[OF_ACCC + s];
    }
    sred[tx] = sum;
    __syncthreads();
    for (int k = 128; k > 0; k >>= 1) {
        if (tx < k) sred[tx] += sred[tx + k];
        __syncthreads();
    }
    if (tx == 0) {
        float loss = sred[0] / (float)NS;
        int fk = ((const int*)ws)[0];
        if (fk) ((__hip_bfloat16*)out)[0] = __float2bfloat16(loss);
        else    ((float*)out)[0] = loss;
    }
}

extern "C" void kernel_launch(void* const* d_in, const int* in_sizes, int n_in,
                              void* d_out, int out_size, void* d_ws, size_t ws_size,
                              hipStream_t stream) {
    const void* features = d_in[0];
    const void* W1   = d_in[1];
    const void* b1   = d_in[2];
    const void* W2   = d_in[3];
    const void* b2   = d_in[4];
    const void* keyw = d_in[5];
    const void* sel  = d_in[6];
    const void* proof = d_in[7];
    float* ws = (float*)d_ws;

    k_probe<<<1, 256, 0, stream>>>(features, W1, b1, W2, b2, keyw, sel, ws);
    int nblk = (NC + 255) / 256;
    k_logits<<<nblk, 256, 0, stream>>>(features, ws);
    k_prep<<<nblk, 256, 0, stream>>>(proof, ws);
    dim3 gB((NC + BL_N - 1) / BL_N, NS / SG);
    k_phaseB<<<gB, 256, 0, stream>>>(sel, ws);
    k_final<<<1, 256, 0, stream>>>(ws, d_out);
}

// Round 2
// 699.864 us; speedup vs baseline: 1.0960x; 1.0960x over previous
//
#include <hip/hip_runtime.h>
#include <hip/hip_bf16.h>

#define DEV __device__ __forceinline__

constexpr int NC = 200000;   // clauses
constexpr int NF = 64;       // features
constexpr int NH = 128;      // hidden
constexpr int NS = 512;      // SEL steps

// ---- workspace layout (float units) ----
constexpr int OF_CFG   = 0;                 // int[16]: [0]=float_kind(0=f32,1=bf16), [1]=mask_width(1/2/4 bytes)
constexpr int OF_W1    = 16;                // 8192 fp32, TRANSPOSED: [(jc*64 + f)*4 + c], jc=hidden/4, f=feature
constexpr int OF_B1    = OF_W1 + NF * NH;   // 128
constexpr int OF_W2K   = OF_B1 + NH;        // 128  (W2 @ key_w)
constexpr int OF_B2K   = OF_W2K + NH;       // 1    (b2 . key_w)
constexpr int OF_MAX   = OF_B2K + 1;        // 1    (flipped-uint global max of logits)
constexpr int OF_ACCE  = OF_MAX + 1;        // 512  sum exp(l-M) over passive
constexpr int OF_ACCP  = OF_ACCE + NS;      // 512  sum logits over passive&proof
constexpr int OF_ACCC  = OF_ACCP + NS;      // 512  count passive&proof
constexpr int OF_LOGIT = 16384;             // 200000
constexpr int OF_E     = OF_LOGIT + NC;     // 200000 exp(l-M)
constexpr int OF_PL    = OF_E + NC;         // 200000 proof? l : 0
constexpr int OF_PC    = OF_PL + NC;        // 200000 proof? 1 : 0
// total = OF_PC + NC = 816384 floats = ~3.2 MB of d_ws

DEV float bf2f(unsigned short u) { return __uint_as_float(((unsigned)u) << 16); }

DEV float loadF(const void* p, int i, int fk) {
    return fk ? bf2f(((const unsigned short*)p)[i]) : ((const float*)p)[i];
}

// order-preserving float->uint map for atomicMax
DEV unsigned flipf(float x) {
    unsigned u = __float_as_uint(x);
    return (u & 0x80000000u) ? ~u : (u | 0x80000000u);
}
DEV float unflipf(unsigned u) {
    unsigned b = (u & 0x80000000u) ? (u ^ 0x80000000u) : ~u;
    return __uint_as_float(b);
}

DEV bool okhalf(unsigned h) { return h == 0u || h == 1u || h == 0x3F80u || h == 0x3C00u; }

// ---------------- K0: parallel dtype probe + small precompute + zero accumulators ----------------
__global__ void k_probe(const void* features, const void* W1, const void* b1,
                        const void* W2, const void* b2, const void* keyw,
                        const void* sel, float* ws) {
    __shared__ int s_tiny, s_w4, s_w2;
    __shared__ float kw[NH];
    __shared__ float pr[NH];
    int tx = threadIdx.x;
    if (tx == 0) { s_tiny = 0; s_w4 = 1; s_w2 = 1; }
    __syncthreads();
    // parallel probe: 256 lanes each check one u16 of features / one u32 of sel
    {
        const unsigned short* u = (const unsigned short*)features;
        unsigned e = (u[tx] >> 7) & 0xFFu;     // exponent field as-if bf16
        if (e < 100u) atomicAdd(&s_tiny, 1);   // fp32 low-halves: ~39% tiny; bf16 N(0,1): ~0
        const unsigned* w = (const unsigned*)sel;
        unsigned v = w[tx];
        if (!(v == 0u || v == 1u || v == 0x3F800000u)) atomicAnd(&s_w4, 0);
        if (!(okhalf(v & 0xFFFFu) && okhalf(v >> 16))) atomicAnd(&s_w2, 0);
    }
    __syncthreads();
    int fk = (s_tiny >= 8) ? 0 : 1;                   // 0=fp32, 1=bf16
    int mw = s_w4 ? 4 : (s_w2 ? 2 : 1);               // mask element bytes
    if (tx == 0) { ((int*)ws)[0] = fk; ((int*)ws)[1] = mw; }
    if (tx < NH) kw[tx] = loadF(keyw, tx, fk);
    // W1 converted + transposed so k_logits' uniform scalar reads are sequential:
    // W1t[(jc*NF + f)*4 + c] = W1[f*NH + jc*4 + c]
    for (int i = tx; i < NF * NH; i += blockDim.x) {
        int f = i >> 7;           // i / NH
        int j = i & (NH - 1);     // i % NH
        int jc = j >> 2, c = j & 3;
        ws[OF_W1 + ((jc * NF + f) << 2) + c] = loadF(W1, i, fk);
    }
    if (tx < NH) ws[OF_B1 + tx] = loadF(b1, tx, fk);
    __syncthreads();
    if (tx < NH) {
        float s = 0.f;
        for (int k = 0; k < NH; k++) s += loadF(W2, tx * NH + k, fk) * kw[k];
        ws[OF_W2K + tx] = s;
        pr[tx] = loadF(b2, tx, fk) * kw[tx];
    }
    __syncthreads();
    if (tx == 0) {
        float s = 0.f;
        for (int k = 0; k < NH; k++) s += pr[k];
        ws[OF_B2K] = s;
        ((unsigned*)ws)[OF_MAX] = 0u;  // flipped -inf sentinel
    }
    for (int i = tx; i < 3 * NS; i += blockDim.x) ws[OF_ACCE + i] = 0.f;
}

// ---------------- K1: logits[n] = relu(F@W1+b1).w2k + b2k, + global max ----------------
// W1t/b1/wk accessed with wave-uniform indices from global -> compiler emits s_load
// (scalar pipe co-issues with VALU; removes the 6.4M-ds_read LDS bottleneck of R1).
__global__ __launch_bounds__(256) void k_logits(const void* features,
                                                const float* __restrict__ w1t,
                                                const float* __restrict__ bias1,
                                                const float* __restrict__ wk,
                                                const float* __restrict__ cfg,
                                                float* __restrict__ logits,
                                                unsigned* __restrict__ maxp) {
    __shared__ float sred[4];
    int tx = threadIdx.x;
    int fk = ((const int*)cfg)[0];
    float b2k = cfg[OF_B2K];
    int n = blockIdx.x * 256 + tx;
    float acc = -3.0e38f;
    if (n < NC) {
        float feat[NF];
        if (fk) {
            const uint4* fp = (const uint4*)((const unsigned short*)features + (size_t)n * NF);
            #pragma unroll
            for (int q = 0; q < 8; q++) {
                uint4 v = fp[q];
                unsigned vv[4] = {v.x, v.y, v.z, v.w};
                #pragma unroll
                for (int h = 0; h < 4; h++) {
                    feat[q * 8 + h * 2 + 0] = __uint_as_float(vv[h] << 16);
                    feat[q * 8 + h * 2 + 1] = __uint_as_float(vv[h] & 0xFFFF0000u);
                }
            }
        } else {
            const float4* fp = (const float4*)((const float*)features + (size_t)n * NF);
            #pragma unroll
            for (int q = 0; q < 16; q++) {
                float4 v = fp[q];
                feat[q * 4 + 0] = v.x; feat[q * 4 + 1] = v.y;
                feat[q * 4 + 2] = v.z; feat[q * 4 + 3] = v.w;
            }
        }
        acc = b2k;
        for (int jc = 0; jc < NH / 4; jc++) {
            const float4* wp = (const float4*)(w1t + (size_t)jc * (NF * 4)); // uniform
            float4 b = *(const float4*)(bias1 + jc * 4);                     // uniform
            float d0 = b.x, d1 = b.y, d2 = b.z, d3 = b.w;
            #pragma unroll
            for (int f = 0; f < NF; f++) {
                float4 w = wp[f];                                            // s_load_dwordx4
                d0 += feat[f] * w.x; d1 += feat[f] * w.y;
                d2 += feat[f] * w.z; d3 += feat[f] * w.w;
            }
            float4 k4 = *(const float4*)(wk + jc * 4);                       // uniform
            acc += fmaxf(d0, 0.f) * k4.x + fmaxf(d1, 0.f) * k4.y
                 + fmaxf(d2, 0.f) * k4.z + fmaxf(d3, 0.f) * k4.w;
        }
        logits[n] = acc;
    }
    // block max -> global atomicMax (flipped uint)
    float m = acc;
    #pragma unroll
    for (int k = 1; k < 64; k <<= 1) m = fmaxf(m, __shfl_xor(m, k, 64));
    if ((tx & 63) == 0) sred[tx >> 6] = m;
    __syncthreads();
    if (tx == 0) {
        m = fmaxf(fmaxf(sred[0], sred[1]), fmaxf(sred[2], sred[3]));
        atomicMax(maxp, flipf(m));
    }
}

// ---------------- K2: e = exp(l - M), proof-gated logits / counts ----------------
__global__ void k_prep(const void* proof, float* ws) {
    int n = blockIdx.x * 256 + threadIdx.x;
    if (n >= NC) return;
    int mw = ((const int*)ws)[1];
    float M = unflipf(((const unsigned*)ws)[OF_MAX]);
    float l = ws[OF_LOGIT + n];
    ws[OF_E + n] = __expf(l - M);
    bool pf;
    if (mw == 1)      pf = ((const unsigned char*)proof)[n] != 0;
    else if (mw == 2) pf = ((const unsigned short*)proof)[n] != 0;
    else              pf = ((const unsigned*)proof)[n] != 0;
    ws[OF_PL + n] = pf ? l : 0.f;
    ws[OF_PC + n] = pf ? 1.f : 0.f;
}

// ---------------- K3: the big masked accumulation over sel_mask ----------------
constexpr int NT_N = 16;            // n per thread (register-resident e/pl/pc)
constexpr int BL_N = 256 * NT_N;    // 4096 n per block
constexpr int SG = 32;              // s per block

template<int MW>
DEV void bloop(const void* sel, int s0, int baddr,
               const float (&e)[NT_N], const float (&pl)[NT_N], const float (&pc)[NT_N],
               float* ws) {
    for (int si = 0; si < SG; si++) {
        int s = s0 + si;
        size_t off = (size_t)s * NC + (size_t)baddr;
        float m[NT_N];
        if (MW == 1) {
            uint4 w = *(const uint4*)((const unsigned char*)sel + off);
            unsigned v[4] = {w.x, w.y, w.z, w.w};
            #pragma unroll
            for (int q = 0; q < 4; q++)
                #pragma unroll
                for (int b = 0; b < 4; b++)
                    m[q * 4 + b] = ((v[q] >> (8 * b)) & 0xFFu) ? 1.f : 0.f;
        } else if (MW == 2) {
            const uint4* p = (const uint4*)((const unsigned short*)sel + off);
            #pragma unroll
            for (int h = 0; h < 2; h++) {
                uint4 w = p[h];
                unsigned v[4] = {w.x, w.y, w.z, w.w};
                #pragma unroll
                for (int q = 0; q < 4; q++) {
                    m[h * 8 + q * 2 + 0] = (v[q] & 0xFFFFu) ? 1.f : 0.f;
                    m[h * 8 + q * 2 + 1] = (v[q] >> 16) ? 1.f : 0.f;
                }
            }
        } else {
            const uint4* p = (const uint4*)((const unsigned*)sel + off);
            #pragma unroll
            for (int q = 0; q < 4; q++) {
                uint4 w = p[q];
                m[q * 4 + 0] = w.x ? 1.f : 0.f; m[q * 4 + 1] = w.y ? 1.f : 0.f;
                m[q * 4 + 2] = w.z ? 1.f : 0.f; m[q * 4 + 3] = w.w ? 1.f : 0.f;
            }
        }
        float se = 0.f, sp = 0.f, sc = 0.f;
        #pragma unroll
        for (int i = 0; i < NT_N; i++) {
            se += m[i] * e[i]; sp += m[i] * pl[i]; sc += m[i] * pc[i];
        }
        #pragma unroll
        for (int k = 1; k < 64; k <<= 1) {
            se += __shfl_xor(se, k, 64);
            sp += __shfl_xor(sp, k, 64);
            sc += __shfl_xor(sc, k, 64);
        }
        if ((threadIdx.x & 63) == 0) {
            atomicAdd(&ws[OF_ACCE + s], se);
            atomicAdd(&ws[OF_ACCP + s], sp);
            atomicAdd(&ws[OF_ACCC + s], sc);
        }
    }
}

__global__ __launch_bounds__(256) void k_phaseB(const void* sel, float* ws) {
    int tx = threadIdx.x;
    int base = blockIdx.x * BL_N + tx * NT_N;
    int s0 = blockIdx.y * SG;
    bool active = base < NC;                 // NC % 16 == 0, so active threads are fully valid
    int baddr = active ? base : 0;
    float e[NT_N], pl[NT_N], pc[NT_N];
    #pragma unroll
    for (int q = 0; q < 4; q++) {
        float4 ve = active ? ((const float4*)&ws[OF_E + baddr])[q]  : make_float4(0, 0, 0, 0);
        float4 vp = active ? ((const float4*)&ws[OF_PL + baddr])[q] : make_float4(0, 0, 0, 0);
        float4 vc = active ? ((const float4*)&ws[OF_PC + baddr])[q] : make_float4(0, 0, 0, 0);
        e[q * 4 + 0] = ve.x; e[q * 4 + 1] = ve.y; e[q * 4 + 2] = ve.z; e[q * 4 + 3] = ve.w;
        pl[q * 4 + 0] = vp.x; pl[q * 4 + 1] = vp.y; pl[q * 4 + 2] = vp.z; pl[q * 4 + 3] = vp.w;
        pc[q * 4 + 0] = vc.x; pc[q * 4 + 1] = vc.y; pc[q * 4 + 2] = vc.z; pc[q * 4 + 3] = vc.w;
    }
    int mw = ((const int*)ws)[1];
    if (mw == 1)      bloop<1>(sel, s0, baddr, e, pl, pc, ws);
    else if (mw == 2) bloop<2>(sel, s0, baddr, e, pl, pc, ws);
    else              bloop<4>(sel, s0, baddr, e, pl, pc, ws);
}

// ---------------- K4: per-step loss + mean, cast to output dtype ----------------
__global__ void k_final(float* ws, void* out) {
    __shared__ float sred[256];
    int tx = threadIdx.x;
    float M = unflipf(((const unsigned*)ws)[OF_MAX]);
    float sum = 0.f;
    for (int s = tx; s < NS; s += 256) {
        float lse = M + logf(ws[OF_ACCE + s]);
        sum += lse - ws[OF_ACCP + s] / ws[OF_ACCC + s];
    }
    sred[tx] = sum;
    __syncthreads();
    for (int k = 128; k > 0; k >>= 1) {
        if (tx < k) sred[tx] += sred[tx + k];
        __syncthreads();
    }
    if (tx == 0) {
        float loss = sred[0] / (float)NS;
        int fk = ((const int*)ws)[0];
        if (fk) ((__hip_bfloat16*)out)[0] = __float2bfloat16(loss);
        else    ((float*)out)[0] = loss;
    }
}

extern "C" void kernel_launch(void* const* d_in, const int* in_sizes, int n_in,
                              void* d_out, int out_size, void* d_ws, size_t ws_size,
                              hipStream_t stream) {
    const void* features = d_in[0];
    const void* W1   = d_in[1];
    const void* b1   = d_in[2];
    const void* W2   = d_in[3];
    const void* b2   = d_in[4];
    const void* keyw = d_in[5];
    const void* sel  = d_in[6];
    const void* proof = d_in[7];
    float* ws = (float*)d_ws;

    k_probe<<<1, 256, 0, stream>>>(features, W1, b1, W2, b2, keyw, sel, ws);
    int nblk = (NC + 255) / 256;
    k_logits<<<nblk, 256, 0, stream>>>(features, ws + OF_W1, ws + OF_B1, ws + OF_W2K,
                                       ws, ws + OF_LOGIT, (unsigned*)ws + OF_MAX);
    k_prep<<<nblk, 256, 0, stream>>>(proof, ws);
    dim3 gB((NC + BL_N - 1) / BL_N, NS / SG);
    k_phaseB<<<gB, 256, 0, stream>>>(sel, ws);
    k_final<<<1, 256, 0, stream>>>(ws, d_out);
}